// Round 3
// baseline (394.140 us; speedup 1.0000x reference)
//
#include <hip/hip_runtime.h>
#include <hip/hip_fp8.h>
#include <stdint.h>
#include <cmath>

using f32x4 = __attribute__((ext_vector_type(4))) float;

#define FP8MAX 448.0f

// ---------------------------------------------------------------- helpers
__device__ __forceinline__ void gload_lds16(const void* g, void* l) {
  __builtin_amdgcn_global_load_lds(
      (const __attribute__((address_space(1))) unsigned int*)g,
      (__attribute__((address_space(3))) unsigned int*)l,
      16, 0, 0);
}

__device__ __forceinline__ uint8_t to_fp8(float v) {
  __hip_fp8_e4m3 q(fminf(fmaxf(v, -FP8MAX), FP8MAX));  // saturating RNE, OCP e4m3fn
  return q.__x;
}

// ---------------------------------------------------------------- W representation detector
// flag = 2: d_in[1] is float32 (fp8 values dequantized to f32)
// flag = 1: d_in[1] is bf16
// flag = 0: d_in[1] is raw fp8 e4m3 bytes
// Discrimination: fp8-exact f32 values have zero low mantissa halves, so
// f32-data passes the f32 round-trip check; bf16-data fails it (nonzero low
// half) but passes the bf16 check; raw bytes fail both over 4096 samples.
__global__ void wdetect(const uint8_t* __restrict__ w, unsigned int* __restrict__ flag) {
  const float* wf = (const float*)w;
  const unsigned short* wh = (const unsigned short*)w;
  int f32ok = 1, bf16ok = 1;
  for (int i = threadIdx.x; i < 4096; i += 256) {
    float v = wf[i];
    if (!(isfinite(v) && fabsf(v) <= FP8MAX)) f32ok = 0;
    else { __hip_fp8_e4m3 q(v); if ((float)q != v) f32ok = 0; }
    float hv = __uint_as_float(((unsigned int)wh[i]) << 16);
    if (!(isfinite(hv) && fabsf(hv) <= FP8MAX)) bf16ok = 0;
    else { __hip_fp8_e4m3 qh(hv); if ((float)qh != hv) bf16ok = 0; }
  }
  __shared__ int sf, sb;
  if (threadIdx.x == 0) { sf = 1; sb = 1; }
  __syncthreads();
  if (!f32ok) atomicAnd(&sf, 0);
  if (!bf16ok) atomicAnd(&sb, 0);
  __syncthreads();
  if (threadIdx.x == 0) *flag = sf ? 2u : (sb ? 1u : 0u);
}

// ---------------------------------------------------------------- W convert -> fp8 bytes
__global__ void wconv(const uint8_t* __restrict__ w, uint8_t* __restrict__ q,
                      const unsigned int* __restrict__ flag_p, int n) {
  unsigned int f = *flag_p;
  int i0 = (blockIdx.x * blockDim.x + threadIdx.x) * 4;
  if (i0 >= n) return;
  uint32_t out;
  if (f == 2) {
    float4 v = *(const float4*)((const float*)w + i0);
    out = (uint32_t)to_fp8(v.x) | ((uint32_t)to_fp8(v.y) << 8) |
          ((uint32_t)to_fp8(v.z) << 16) | ((uint32_t)to_fp8(v.w) << 24);
  } else if (f == 1) {
    ushort4 h = *(const ushort4*)((const unsigned short*)w + i0);
    float a = __uint_as_float(((unsigned int)h.x) << 16);
    float b = __uint_as_float(((unsigned int)h.y) << 16);
    float c = __uint_as_float(((unsigned int)h.z) << 16);
    float d = __uint_as_float(((unsigned int)h.w) << 16);
    out = (uint32_t)to_fp8(a) | ((uint32_t)to_fp8(b) << 8) |
          ((uint32_t)to_fp8(c) << 16) | ((uint32_t)to_fp8(d) << 24);
  } else {
    out = *(const uint32_t*)(w + i0);
  }
  *(uint32_t*)(q + i0) = out;
}

// ---------------------------------------------------------------- pass 1: amax = max(|x|)
__global__ void amax_kernel(const float* __restrict__ x, size_t n4,
                            unsigned int* __restrict__ amax_u) {
  const float4* x4 = (const float4*)x;
  float m = 0.0f;
  size_t stride = (size_t)gridDim.x * blockDim.x;
  for (size_t i = (size_t)blockIdx.x * blockDim.x + threadIdx.x; i < n4; i += stride) {
    float4 v = x4[i];
    m = fmaxf(m, fmaxf(fmaxf(fabsf(v.x), fabsf(v.y)),
                       fmaxf(fabsf(v.z), fabsf(v.w))));
  }
  #pragma unroll
  for (int off = 32; off > 0; off >>= 1)
    m = fmaxf(m, __shfl_xor(m, off));
  __shared__ float sm[16];
  int wid = threadIdx.x >> 6;
  if ((threadIdx.x & 63) == 0) sm[wid] = m;
  __syncthreads();
  if (threadIdx.x == 0) {
    int nw = blockDim.x >> 6;
    float r = sm[0];
    for (int i = 1; i < nw; i++) r = fmaxf(r, sm[i]);
    atomicMax(amax_u, __float_as_uint(r));  // non-negative float bits order-preserving
  }
}

// ---------------------------------------------------------------- pass 2: quantize x -> fp8
__global__ void quant_kernel(const float* __restrict__ x,
                             uint8_t* __restrict__ q,
                             const float* __restrict__ amax_p, size_t n16) {
  float amax = fmaxf(amax_p[0], 1e-12f);
  float scale = FP8MAX / amax;        // reference: FP8_MAX / clip(amax)
  const float4* x4 = (const float4*)x;
  uint4* q16 = (uint4*)q;
  size_t stride = (size_t)gridDim.x * blockDim.x;
  for (size_t i = (size_t)blockIdx.x * blockDim.x + threadIdx.x; i < n16; i += stride) {
    uint32_t w[4];
    #pragma unroll
    for (int j = 0; j < 4; j++) {
      float4 v = x4[i * 4 + j];
      w[j] = (uint32_t)to_fp8(v.x * scale) | ((uint32_t)to_fp8(v.y * scale) << 8) |
             ((uint32_t)to_fp8(v.z * scale) << 16) | ((uint32_t)to_fp8(v.w * scale) << 24);
    }
    uint4 o; o.x = w[0]; o.y = w[1]; o.z = w[2]; o.w = w[3];
    q16[i] = o;
  }
}

// ---------------------------------------------------------------- pass 3: fp8 GEMM
// C[M,N] = s * A[M,K] x B[N,K]^T ; m97/m145 structure: 128x128 tile, BK=64,
// 4 waves (2x2), 16x16x32 fp8 MFMA, global_load_lds w=16, 2-barrier loop.
#define BM 128
#define BN 128
#define BK 64

__global__ __launch_bounds__(256) void gemm_fp8(
    const uint8_t* __restrict__ A,   // [M,K] fp8
    const uint8_t* __restrict__ B,   // [N,K] fp8
    float* __restrict__ C,           // [M,N] f32
    const float* __restrict__ amax_p,
    const float* __restrict__ wscale_p,
    int M, int N, int K) {
  __shared__ uint8_t lds_a[BM * BK];  // 8 KB
  __shared__ uint8_t lds_b[BN * BK];  // 8 KB

  // bijective XCD swizzle (gridDim % 8 == 0): one XCD owns a contiguous
  // run of bm-strips -> each A-strip L2-resident on exactly one XCD.
  int nwg = gridDim.x;
  int cpx = nwg >> 3;
  int swz = (blockIdx.x & 7) * cpx + (blockIdx.x >> 3);

  int nstrips = N / BN;               // 8
  int bm = (swz / nstrips) * BM;
  int bn = (swz % nstrips) * BN;

  int t = threadIdx.x;
  int lane = t & 63;
  int wave = t >> 6;
  int wm = (wave >> 1) * 64;
  int wn = (wave & 1) * 64;

  float amax = fmaxf(amax_p[0], 1e-12f);
  float scale = FP8MAX / amax;
  float s = (1.0f / scale) * wscale_p[0];   // inv_act_scale * weight_scale

  f32x4 acc[4][4] = {};

  // staging: thread t covers tile-row t>>2 (0..63), 16B chunk (t&3); LDS linear
  const uint8_t* ga = A + (size_t)(bm + (t >> 2)) * K + (t & 3) * 16;
  const uint8_t* gb = B + (size_t)(bn + (t >> 2)) * K + (t & 3) * 16;
  uint8_t* la = &lds_a[wave * 1024];
  uint8_t* lb = &lds_b[wave * 1024];

  const uint8_t* pa = &lds_a[(wm + (lane & 15)) * BK + (lane >> 4) * 8];
  const uint8_t* pb = &lds_b[(wn + (lane & 15)) * BK + (lane >> 4) * 8];

  for (int k0 = 0; k0 < K; k0 += BK) {
    __syncthreads();
    gload_lds16(ga + k0,                  la);
    gload_lds16(ga + k0 + (size_t)64 * K, la + 4096);
    gload_lds16(gb + k0,                  lb);
    gload_lds16(gb + k0 + (size_t)64 * K, lb + 4096);
    __syncthreads();   // compiler drains vmcnt before barrier -> LDS ready

    #pragma unroll
    for (int kk = 0; kk < BK; kk += 32) {
      long a[4], b[4];
      #pragma unroll
      for (int i = 0; i < 4; i++)
        a[i] = *(const long*)(pa + (size_t)i * 16 * BK + kk);
      #pragma unroll
      for (int j = 0; j < 4; j++)
        b[j] = *(const long*)(pb + (size_t)j * 16 * BK + kk);
      #pragma unroll
      for (int i = 0; i < 4; i++)
        #pragma unroll
        for (int j = 0; j < 4; j++)
          acc[i][j] = __builtin_amdgcn_mfma_f32_16x16x32_fp8_fp8(
              a[i], b[j], acc[i][j], 0, 0, 0);
    }
  }

  // epilogue: C/D layout col=lane&15, row=(lane>>4)*4+reg  (m89-verified)
  #pragma unroll
  for (int i = 0; i < 4; i++) {
    #pragma unroll
    for (int j = 0; j < 4; j++) {
      int row = bm + wm + i * 16 + (lane >> 4) * 4;
      int col = bn + wn + j * 16 + (lane & 15);
      #pragma unroll
      for (int r = 0; r < 4; r++)
        C[(size_t)(row + r) * N + col] = acc[i][j][r] * s;
    }
  }
}

// ---------------------------------------------------------------- launch
extern "C" void kernel_launch(void* const* d_in, const int* in_sizes, int n_in,
                              void* d_out, int out_size, void* d_ws, size_t ws_size,
                              hipStream_t stream) {
  const float* x = (const float*)d_in[0];
  const uint8_t* wraw = (const uint8_t*)d_in[1];
  const float* wscale = (const float*)d_in[2];
  float* out = (float*)d_out;

  long long in0 = in_sizes[0];   // M*K
  long long in1 = in_sizes[1];   // N*K
  double kd = sqrt((double)in0 * (double)in1 / (double)out_size);
  long long K = (long long)(kd + 0.5);
  long long M = in0 / K;
  long long N = in1 / K;

  // ws layout: [0,4) amax bits | [64,68) wflag | [4096, 4096+1MB) qw | [2MB, 2MB+64MB) qx
  unsigned int* amax_u = (unsigned int*)d_ws;
  const float* amax_f = (const float*)d_ws;
  unsigned int* wflag = (unsigned int*)((uint8_t*)d_ws + 64);
  uint8_t* qw = (uint8_t*)d_ws + 4096;
  uint8_t* qx = (uint8_t*)d_ws + (2u << 20);

  hipMemsetAsync(d_ws, 0, 4, stream);   // zero amax slot
  wdetect<<<1, 256, 0, stream>>>(wraw, wflag);
  wconv<<<(unsigned)(in1 / 4 / 256), 256, 0, stream>>>(wraw, qw, wflag, (int)in1);
  amax_kernel<<<2048, 256, 0, stream>>>(x, (size_t)(in0 / 4), amax_u);
  quant_kernel<<<2048, 256, 0, stream>>>(x, qx, amax_f, (size_t)(in0 / 16));

  dim3 grid((unsigned)((M / BM) * (N / BN)));
  gemm_fp8<<<grid, 256, 0, stream>>>(qx, qw, out, amax_f, wscale,
                                     (int)M, (int)N, (int)K);
}

// Round 4
// 314.441 us; speedup vs baseline: 1.2535x; 1.2535x over previous
//
#include <hip/hip_runtime.h>
#include <hip/hip_fp8.h>
#include <stdint.h>
#include <cmath>

using f32x4 = __attribute__((ext_vector_type(4))) float;

#define FP8MAX 448.0f

// ---------------------------------------------------------------- helpers
__device__ __forceinline__ void gload_lds16(const void* g, void* l) {
  __builtin_amdgcn_global_load_lds(
      (const __attribute__((address_space(1))) unsigned int*)g,
      (__attribute__((address_space(3))) unsigned int*)l,
      16, 0, 0);
}

__device__ __forceinline__ uint8_t to_fp8(float v) {
  __hip_fp8_e4m3 q(fminf(fmaxf(v, -FP8MAX), FP8MAX));  // saturating RNE, OCP e4m3fn
  return q.__x;
}

// ---------------------------------------------------------------- W representation detector
// flag = 2: d_in[1] is float32 of fp8-exact values; 1: bf16; 0: raw fp8 bytes
__global__ void wdetect(const uint8_t* __restrict__ w, unsigned int* __restrict__ flag) {
  const float* wf = (const float*)w;
  const unsigned short* wh = (const unsigned short*)w;
  int f32ok = 1, bf16ok = 1;
  for (int i = threadIdx.x; i < 4096; i += 256) {
    float v = wf[i];
    if (!(isfinite(v) && fabsf(v) <= FP8MAX)) f32ok = 0;
    else { __hip_fp8_e4m3 q(v); if ((float)q != v) f32ok = 0; }
    float hv = __uint_as_float(((unsigned int)wh[i]) << 16);
    if (!(isfinite(hv) && fabsf(hv) <= FP8MAX)) bf16ok = 0;
    else { __hip_fp8_e4m3 qh(hv); if ((float)qh != hv) bf16ok = 0; }
  }
  __shared__ int sf, sb;
  if (threadIdx.x == 0) { sf = 1; sb = 1; }
  __syncthreads();
  if (!f32ok) atomicAnd(&sf, 0);
  if (!bf16ok) atomicAnd(&sb, 0);
  __syncthreads();
  if (threadIdx.x == 0) *flag = sf ? 2u : (sb ? 1u : 0u);
}

// ---------------------------------------------------------------- W convert -> fp8 bytes
__global__ void wconv(const uint8_t* __restrict__ w, uint8_t* __restrict__ q,
                      const unsigned int* __restrict__ flag_p, int n) {
  unsigned int f = *flag_p;
  int i0 = (blockIdx.x * blockDim.x + threadIdx.x) * 4;
  if (i0 >= n) return;
  uint32_t out;
  if (f == 2) {
    float4 v = *(const float4*)((const float*)w + i0);
    out = (uint32_t)to_fp8(v.x) | ((uint32_t)to_fp8(v.y) << 8) |
          ((uint32_t)to_fp8(v.z) << 16) | ((uint32_t)to_fp8(v.w) << 24);
  } else if (f == 1) {
    ushort4 h = *(const ushort4*)((const unsigned short*)w + i0);
    float a = __uint_as_float(((unsigned int)h.x) << 16);
    float b = __uint_as_float(((unsigned int)h.y) << 16);
    float c = __uint_as_float(((unsigned int)h.z) << 16);
    float d = __uint_as_float(((unsigned int)h.w) << 16);
    out = (uint32_t)to_fp8(a) | ((uint32_t)to_fp8(b) << 8) |
          ((uint32_t)to_fp8(c) << 16) | ((uint32_t)to_fp8(d) << 24);
  } else {
    out = *(const uint32_t*)(w + i0);
  }
  *(uint32_t*)(q + i0) = out;
}

// ---------------------------------------------------------------- pass 1: amax = max(|x|)
__global__ void amax_kernel(const float* __restrict__ x, size_t n4,
                            unsigned int* __restrict__ amax_u) {
  const float4* x4 = (const float4*)x;
  float m = 0.0f;
  size_t stride = (size_t)gridDim.x * blockDim.x;
  for (size_t i = (size_t)blockIdx.x * blockDim.x + threadIdx.x; i < n4; i += stride) {
    float4 v = x4[i];
    m = fmaxf(m, fmaxf(fmaxf(fabsf(v.x), fabsf(v.y)),
                       fmaxf(fabsf(v.z), fabsf(v.w))));
  }
  #pragma unroll
  for (int off = 32; off > 0; off >>= 1)
    m = fmaxf(m, __shfl_xor(m, off));
  __shared__ float sm[16];
  int wid = threadIdx.x >> 6;
  if ((threadIdx.x & 63) == 0) sm[wid] = m;
  __syncthreads();
  if (threadIdx.x == 0) {
    int nw = blockDim.x >> 6;
    float r = sm[0];
    for (int i = 1; i < nw; i++) r = fmaxf(r, sm[i]);
    atomicMax(amax_u, __float_as_uint(r));  // non-negative float bits order-preserving
  }
}

// ---------------------------------------------------------------- pass 2: quantize x -> fp8
__global__ void quant_kernel(const float* __restrict__ x,
                             uint8_t* __restrict__ q,
                             const float* __restrict__ amax_p, size_t n16) {
  float amax = fmaxf(amax_p[0], 1e-12f);
  float scale = FP8MAX / amax;        // reference: FP8_MAX / clip(amax)
  const float4* x4 = (const float4*)x;
  uint4* q16 = (uint4*)q;
  size_t stride = (size_t)gridDim.x * blockDim.x;
  for (size_t i = (size_t)blockIdx.x * blockDim.x + threadIdx.x; i < n16; i += stride) {
    uint32_t w[4];
    #pragma unroll
    for (int j = 0; j < 4; j++) {
      float4 v = x4[i * 4 + j];
      w[j] = (uint32_t)to_fp8(v.x * scale) | ((uint32_t)to_fp8(v.y * scale) << 8) |
             ((uint32_t)to_fp8(v.z * scale) << 16) | ((uint32_t)to_fp8(v.w * scale) << 24);
    }
    uint4 o; o.x = w[0]; o.y = w[1]; o.z = w[2]; o.w = w[3];
    q16[i] = o;
  }
}

// ---------------------------------------------------------------- pass 3: fp8 GEMM
// C[M,N] = s * A[M,K] x B[N,K]^T.  128x128 tile, BK=128 (row stride 128B ==
// 0 mod 32 banks), 4 waves (2x2), 16x16x32 fp8 MFMA.
// T2 swizzle under global_load_lds (rule #21): LDS dest linear, global
// source chunk pre-swizzled chunk^=(row&7), reads XOR the same way ->
// conflict-free ds_read_b64 (2 lanes/bank).
#define BM 128
#define BN 128
#define BK 128

__global__ __launch_bounds__(256) void gemm_fp8(
    const uint8_t* __restrict__ A,   // [M,K] fp8
    const uint8_t* __restrict__ B,   // [N,K] fp8
    float* __restrict__ C,           // [M,N] f32
    const float* __restrict__ amax_p,
    const float* __restrict__ wscale_p,
    int M, int N, int K) {
  __shared__ uint8_t lds_a[BM * BK];  // 16 KB
  __shared__ uint8_t lds_b[BN * BK];  // 16 KB

  // bijective XCD swizzle (gridDim % 8 == 0)
  int nwg = gridDim.x;
  int cpx = nwg >> 3;
  int swz = (blockIdx.x & 7) * cpx + (blockIdx.x >> 3);

  int nstrips = N / BN;               // 8
  int bm = (swz / nstrips) * BM;
  int bn = (swz % nstrips) * BN;

  int t = threadIdx.x;
  int lane = t & 63;
  int wave = t >> 6;
  int wm = (wave >> 1) * 64;
  int wn = (wave & 1) * 64;

  float amax = fmaxf(amax_p[0], 1e-12f);
  float scale = FP8MAX / amax;
  float s = (1.0f / scale) * wscale_p[0];   // inv_act_scale * weight_scale

  f32x4 acc[4][4] = {};

  // staging: pass p covers rows p*32..p*32+31; thread t -> row p*32+(t>>3),
  // LDS chunk t&7 (linear dest t*16 within pass), global chunk (t&7)^(row&7)
  const int rt = t >> 3;
  const int ct = t & 7;
  uint8_t* la = &lds_a[wave * 1024];
  uint8_t* lb = &lds_b[wave * 1024];

  // fragment read: row & lane-group constants
  const int lr = lane & 15;           // row-in-fragment
  const int kg = (lane >> 4) * 8;     // 0,8,16,24
  // arow&7 == lr&7 for all fragments (wm, i*16 are multiples of 8)
  const int x7 = lr & 7;

  for (int k0 = 0; k0 < K; k0 += BK) {
    __syncthreads();
    #pragma unroll
    for (int p = 0; p < 4; ++p) {
      int r = p * 32 + rt;
      int gc = (ct ^ (r & 7)) * 16;
      gload_lds16(A + (size_t)(bm + r) * K + k0 + gc, la + p * 4096);
      gload_lds16(B + (size_t)(bn + r) * K + k0 + gc, lb + p * 4096);
    }
    __syncthreads();   // compiler drains vmcnt before barrier -> LDS ready

    #pragma unroll
    for (int kk = 0; kk < BK; kk += 32) {
      const int koff = kk + kg;
      const int cswz = (((koff >> 4) ^ x7) << 4) + (koff & 15);
      long a[4], b[4];
      #pragma unroll
      for (int i = 0; i < 4; i++)
        a[i] = *(const long*)&lds_a[(wm + i * 16 + lr) * BK + cswz];
      #pragma unroll
      for (int j = 0; j < 4; j++)
        b[j] = *(const long*)&lds_b[(wn + j * 16 + lr) * BK + cswz];
      #pragma unroll
      for (int i = 0; i < 4; i++)
        #pragma unroll
        for (int j = 0; j < 4; j++)
          acc[i][j] = __builtin_amdgcn_mfma_f32_16x16x32_fp8_fp8(
              a[i], b[j], acc[i][j], 0, 0, 0);
    }
  }

  // epilogue: C/D layout col=lane&15, row=(lane>>4)*4+reg  (m89-verified)
  #pragma unroll
  for (int i = 0; i < 4; i++) {
    #pragma unroll
    for (int j = 0; j < 4; j++) {
      int row = bm + wm + i * 16 + (lane >> 4) * 4;
      int col = bn + wn + j * 16 + (lane & 15);
      #pragma unroll
      for (int r = 0; r < 4; r++)
        C[(size_t)(row + r) * N + col] = acc[i][j][r] * s;
    }
  }
}

// ---------------------------------------------------------------- launch
extern "C" void kernel_launch(void* const* d_in, const int* in_sizes, int n_in,
                              void* d_out, int out_size, void* d_ws, size_t ws_size,
                              hipStream_t stream) {
  const float* x = (const float*)d_in[0];
  const uint8_t* wraw = (const uint8_t*)d_in[1];
  const float* wscale = (const float*)d_in[2];
  float* out = (float*)d_out;

  long long in0 = in_sizes[0];   // M*K
  long long in1 = in_sizes[1];   // N*K
  double kd = sqrt((double)in0 * (double)in1 / (double)out_size);
  long long K = (long long)(kd + 0.5);
  long long M = in0 / K;
  long long N = in1 / K;

  // ws layout: [0,4) amax | [64,68) wflag | [4096,+1MB) qw | [2MB,+64MB) qx
  unsigned int* amax_u = (unsigned int*)d_ws;
  const float* amax_f = (const float*)d_ws;
  unsigned int* wflag = (unsigned int*)((uint8_t*)d_ws + 64);
  uint8_t* qw = (uint8_t*)d_ws + 4096;
  uint8_t* qx = (uint8_t*)d_ws + (2u << 20);

  hipMemsetAsync(d_ws, 0, 4, stream);   // zero amax slot
  wdetect<<<1, 256, 0, stream>>>(wraw, wflag);
  wconv<<<(unsigned)(in1 / 4 / 256), 256, 0, stream>>>(wraw, qw, wflag, (int)in1);
  amax_kernel<<<2048, 256, 0, stream>>>(x, (size_t)(in0 / 4), amax_u);
  quant_kernel<<<2048, 256, 0, stream>>>(x, qx, amax_f, (size_t)(in0 / 16));

  dim3 grid((unsigned)((M / BM) * (N / BN)));
  gemm_fp8<<<grid, 256, 0, stream>>>(qx, qw, out, amax_f, wscale,
                                     (int)M, (int)N, (int)K);
}

// Round 5
// 277.553 us; speedup vs baseline: 1.4201x; 1.1329x over previous
//
#include <hip/hip_runtime.h>
#include <hip/hip_fp8.h>
#include <stdint.h>
#include <cmath>

using f32x4 = __attribute__((ext_vector_type(4))) float;
using i32x4 = __attribute__((ext_vector_type(4))) int;
using i32x8 = __attribute__((ext_vector_type(8))) int;

#define FP8MAX 448.0f

// ---------------------------------------------------------------- helpers
__device__ __forceinline__ void gload_lds16(const void* g, void* l) {
  __builtin_amdgcn_global_load_lds(
      (const __attribute__((address_space(1))) unsigned int*)g,
      (__attribute__((address_space(3))) unsigned int*)l,
      16, 0, 0);
}

__device__ __forceinline__ uint8_t to_fp8(float v) {
  __hip_fp8_e4m3 q(fminf(fmaxf(v, -FP8MAX), FP8MAX));  // saturating RNE, OCP e4m3fn
  return q.__x;
}

// ---------------------------------------------------------------- W representation detector
// flag = 2: d_in[1] is float32 of fp8-exact values; 1: bf16; 0: raw fp8 bytes
__global__ void wdetect(const uint8_t* __restrict__ w, unsigned int* __restrict__ flag) {
  const float* wf = (const float*)w;
  const unsigned short* wh = (const unsigned short*)w;
  int f32ok = 1, bf16ok = 1;
  for (int i = threadIdx.x; i < 4096; i += 256) {
    float v = wf[i];
    if (!(isfinite(v) && fabsf(v) <= FP8MAX)) f32ok = 0;
    else { __hip_fp8_e4m3 q(v); if ((float)q != v) f32ok = 0; }
    float hv = __uint_as_float(((unsigned int)wh[i]) << 16);
    if (!(isfinite(hv) && fabsf(hv) <= FP8MAX)) bf16ok = 0;
    else { __hip_fp8_e4m3 qh(hv); if ((float)qh != hv) bf16ok = 0; }
  }
  __shared__ int sf, sb;
  if (threadIdx.x == 0) { sf = 1; sb = 1; }
  __syncthreads();
  if (!f32ok) atomicAnd(&sf, 0);
  if (!bf16ok) atomicAnd(&sb, 0);
  __syncthreads();
  if (threadIdx.x == 0) *flag = sf ? 2u : (sb ? 1u : 0u);
}

// ---------------------------------------------------------------- W convert -> fp8 bytes
__global__ void wconv(const uint8_t* __restrict__ w, uint8_t* __restrict__ q,
                      const unsigned int* __restrict__ flag_p, int n) {
  unsigned int f = *flag_p;
  int i0 = (blockIdx.x * blockDim.x + threadIdx.x) * 4;
  if (i0 >= n) return;
  uint32_t out;
  if (f == 2) {
    float4 v = *(const float4*)((const float*)w + i0);
    out = (uint32_t)to_fp8(v.x) | ((uint32_t)to_fp8(v.y) << 8) |
          ((uint32_t)to_fp8(v.z) << 16) | ((uint32_t)to_fp8(v.w) << 24);
  } else if (f == 1) {
    ushort4 h = *(const ushort4*)((const unsigned short*)w + i0);
    float a = __uint_as_float(((unsigned int)h.x) << 16);
    float b = __uint_as_float(((unsigned int)h.y) << 16);
    float c = __uint_as_float(((unsigned int)h.z) << 16);
    float d = __uint_as_float(((unsigned int)h.w) << 16);
    out = (uint32_t)to_fp8(a) | ((uint32_t)to_fp8(b) << 8) |
          ((uint32_t)to_fp8(c) << 16) | ((uint32_t)to_fp8(d) << 24);
  } else {
    out = *(const uint32_t*)(w + i0);
  }
  *(uint32_t*)(q + i0) = out;
}

// ---------------------------------------------------------------- pass 1: amax = max(|x|)
__global__ void amax_kernel(const float* __restrict__ x, size_t n4,
                            unsigned int* __restrict__ amax_u) {
  const float4* x4 = (const float4*)x;
  float m = 0.0f;
  size_t stride = (size_t)gridDim.x * blockDim.x;
  for (size_t i = (size_t)blockIdx.x * blockDim.x + threadIdx.x; i < n4; i += stride) {
    float4 v = x4[i];
    m = fmaxf(m, fmaxf(fmaxf(fabsf(v.x), fabsf(v.y)),
                       fmaxf(fabsf(v.z), fabsf(v.w))));
  }
  #pragma unroll
  for (int off = 32; off > 0; off >>= 1)
    m = fmaxf(m, __shfl_xor(m, off));
  __shared__ float sm[16];
  int wid = threadIdx.x >> 6;
  if ((threadIdx.x & 63) == 0) sm[wid] = m;
  __syncthreads();
  if (threadIdx.x == 0) {
    int nw = blockDim.x >> 6;
    float r = sm[0];
    for (int i = 1; i < nw; i++) r = fmaxf(r, sm[i]);
    atomicMax(amax_u, __float_as_uint(r));  // non-negative float bits order-preserving
  }
}

// ---------------------------------------------------------------- pass 2: quantize x -> fp8
__global__ void quant_kernel(const float* __restrict__ x,
                             uint8_t* __restrict__ q,
                             const float* __restrict__ amax_p, size_t n16) {
  float amax = fmaxf(amax_p[0], 1e-12f);
  float scale = FP8MAX / amax;        // reference: FP8_MAX / clip(amax)
  const float4* x4 = (const float4*)x;
  uint4* q16 = (uint4*)q;
  size_t stride = (size_t)gridDim.x * blockDim.x;
  for (size_t i = (size_t)blockIdx.x * blockDim.x + threadIdx.x; i < n16; i += stride) {
    uint32_t w[4];
    #pragma unroll
    for (int j = 0; j < 4; j++) {
      float4 v = x4[i * 4 + j];
      w[j] = (uint32_t)to_fp8(v.x * scale) | ((uint32_t)to_fp8(v.y * scale) << 8) |
             ((uint32_t)to_fp8(v.z * scale) << 16) | ((uint32_t)to_fp8(v.w * scale) << 24);
    }
    uint4 o; o.x = w[0]; o.y = w[1]; o.z = w[2]; o.w = w[3];
    q16[i] = o;
  }
}

// ---------------------------------------------------------------- pass 3: MX-fp8 GEMM (unit scales)
// C[M,N] = s * A[M,K] x B[N,K]^T.  128x128 tile, BK=128, 4 waves (2x2),
// mfma_scale_f32_16x16x128_f8f6f4 with E8M0 scale 0x7F (=1.0): numerically
// identical to non-scaled fp8, 2x the MFMA rate (m148: 1628 TF on this
// structure).  Fragment: row=lane&15, k=(lane>>4)*32+idx (lane-group g holds
// MX K-block g).  T2 swizzle under global_load_lds (rule #21): linear LDS
// dest, global source chunk ^= (row&7), reads XOR the same way.
#define BM 128
#define BN 128
#define BK 128

__global__ __launch_bounds__(256) void gemm_fp8(
    const uint8_t* __restrict__ A,   // [M,K] fp8
    const uint8_t* __restrict__ B,   // [N,K] fp8
    float* __restrict__ C,           // [M,N] f32
    const float* __restrict__ amax_p,
    const float* __restrict__ wscale_p,
    int M, int N, int K) {
  __shared__ uint8_t lds_a[BM * BK];  // 16 KB
  __shared__ uint8_t lds_b[BN * BK];  // 16 KB

  // bijective XCD swizzle (gridDim % 8 == 0)
  int nwg = gridDim.x;
  int cpx = nwg >> 3;
  int swz = (blockIdx.x & 7) * cpx + (blockIdx.x >> 3);

  int nstrips = N / BN;               // 8
  int bm = (swz / nstrips) * BM;
  int bn = (swz % nstrips) * BN;

  int t = threadIdx.x;
  int lane = t & 63;
  int wave = t >> 6;
  int wm = (wave >> 1) * 64;
  int wn = (wave & 1) * 64;

  float amax = fmaxf(amax_p[0], 1e-12f);
  float scale = FP8MAX / amax;
  float s = (1.0f / scale) * wscale_p[0];   // inv_act_scale * weight_scale

  f32x4 acc[4][4] = {};

  // staging: pass p covers rows p*32..p*32+31; thread t -> row p*32+(t>>3),
  // LDS linear dest t*16 within pass, global chunk (t&7)^(row&7)
  const int rt = t >> 3;
  const int ct = t & 7;
  uint8_t* la = &lds_a[wave * 1024];
  uint8_t* lb = &lds_b[wave * 1024];

  // fragment read constants
  const int lr = lane & 15;           // row-in-fragment
  const int x7 = lr & 7;              // rows wm+i*16+lr have row&7 == lr&7
  const int g2 = (lane >> 4) << 1;    // 16B-chunk pair base: 0,2,4,6
  const int c0 = ((g2 ^ x7) << 4);
  const int c1 = (((g2 + 1) ^ x7) << 4);
  int abase[4], bbase[4];
  #pragma unroll
  for (int i = 0; i < 4; i++) abase[i] = (wm + i * 16 + lr) * BK;
  #pragma unroll
  for (int j = 0; j < 4; j++) bbase[j] = (wn + j * 16 + lr) * BK;

  for (int k0 = 0; k0 < K; k0 += BK) {
    __syncthreads();
    #pragma unroll
    for (int p = 0; p < 4; ++p) {
      int r = p * 32 + rt;
      int gc = (ct ^ (r & 7)) * 16;
      gload_lds16(A + (size_t)(bm + r) * K + k0 + gc, la + p * 4096);
      gload_lds16(B + (size_t)(bn + r) * K + k0 + gc, lb + p * 4096);
    }
    __syncthreads();   // compiler drains vmcnt before barrier -> LDS ready

    i32x8 af[4], bf[4];
    #pragma unroll
    for (int i = 0; i < 4; i++) {
      i32x4 lo = *(const i32x4*)&lds_a[abase[i] + c0];
      i32x4 hi = *(const i32x4*)&lds_a[abase[i] + c1];
      af[i] = (i32x8){lo.x, lo.y, lo.z, lo.w, hi.x, hi.y, hi.z, hi.w};
    }
    #pragma unroll
    for (int j = 0; j < 4; j++) {
      i32x4 lo = *(const i32x4*)&lds_b[bbase[j] + c0];
      i32x4 hi = *(const i32x4*)&lds_b[bbase[j] + c1];
      bf[j] = (i32x8){lo.x, lo.y, lo.z, lo.w, hi.x, hi.y, hi.z, hi.w};
    }
    #pragma unroll
    for (int i = 0; i < 4; i++)
      #pragma unroll
      for (int j = 0; j < 4; j++)
        acc[i][j] = __builtin_amdgcn_mfma_scale_f32_16x16x128_f8f6f4(
            af[i], bf[j], acc[i][j],
            0 /*A=fp8*/, 0 /*B=fp8*/,
            0, 0x7f7f7f7f,   // scale_A opsel, E8M0 1.0
            0, 0x7f7f7f7f);  // scale_B opsel, E8M0 1.0
  }

  // epilogue: C/D layout col=lane&15, row=(lane>>4)*4+reg (shape-determined)
  #pragma unroll
  for (int i = 0; i < 4; i++) {
    #pragma unroll
    for (int j = 0; j < 4; j++) {
      int row = bm + wm + i * 16 + (lane >> 4) * 4;
      int col = bn + wn + j * 16 + (lane & 15);
      #pragma unroll
      for (int r = 0; r < 4; r++)
        C[(size_t)(row + r) * N + col] = acc[i][j][r] * s;
    }
  }
}

// ---------------------------------------------------------------- launch
extern "C" void kernel_launch(void* const* d_in, const int* in_sizes, int n_in,
                              void* d_out, int out_size, void* d_ws, size_t ws_size,
                              hipStream_t stream) {
  const float* x = (const float*)d_in[0];
  const uint8_t* wraw = (const uint8_t*)d_in[1];
  const float* wscale = (const float*)d_in[2];
  float* out = (float*)d_out;

  long long in0 = in_sizes[0];   // M*K
  long long in1 = in_sizes[1];   // N*K
  double kd = sqrt((double)in0 * (double)in1 / (double)out_size);
  long long K = (long long)(kd + 0.5);
  long long M = in0 / K;
  long long N = in1 / K;

  // ws layout: [0,4) amax | [64,68) wflag | [4096,+1MB) qw | [2MB,+64MB) qx
  unsigned int* amax_u = (unsigned int*)d_ws;
  const float* amax_f = (const float*)d_ws;
  unsigned int* wflag = (unsigned int*)((uint8_t*)d_ws + 64);
  uint8_t* qw = (uint8_t*)d_ws + 4096;
  uint8_t* qx = (uint8_t*)d_ws + (2u << 20);

  hipMemsetAsync(d_ws, 0, 4, stream);   // zero amax slot
  wdetect<<<1, 256, 0, stream>>>(wraw, wflag);
  wconv<<<(unsigned)(in1 / 4 / 256), 256, 0, stream>>>(wraw, qw, wflag, (int)in1);
  amax_kernel<<<2048, 256, 0, stream>>>(x, (size_t)(in0 / 4), amax_u);
  quant_kernel<<<2048, 256, 0, stream>>>(x, qx, amax_f, (size_t)(in0 / 16));

  dim3 grid((unsigned)((M / BM) * (N / BN)));
  gemm_fp8<<<grid, 256, 0, stream>>>(qx, qw, out, amax_f, wscale,
                                     (int)M, (int)N, (int)K);
}